// Round 1
// 1984.708 us; speedup vs baseline: 1.1994x; 1.1994x over previous
//
#include <hip/hip_runtime.h>
#include <hip/hip_bf16.h>

// Shapes (fixed): T=4, B=16, C=256 (gate/filt each), O=2C=512 conv-out, L=2048.
// TAU=1.2, VTH=0.5. Spikes are exactly (v >= 0.5) in forward.
// z = sigmoid(gate)*tanh(filt) with gate,filt in {0,1} -> z in {0, Z01, Z11}.

#define T_STEPS 4
#define BB 16
#define C_CH 256
#define O_CH 512
#define LL 2048
#define OUT_HALF 33554432  // T*B*C*L

// ---------------- Kernel A: embedding MLP -> proj -> pk[b][o][k] ----------------
__global__ __launch_bounds__(256) void embed_proj_kernel(
    const int* __restrict__ dstep,
    const float* __restrict__ w_emb1, const float* __restrict__ b_emb1,
    const float* __restrict__ w_emb2, const float* __restrict__ b_emb2,
    const float* __restrict__ w_proj, const float* __restrict__ b_proj,
    const float* __restrict__ w_conv, const float* __restrict__ b_conv,
    float* __restrict__ pk)
{
    const int b = blockIdx.x;
    const int tid = threadIdx.x;
    __shared__ float h[256], emb[256], proj[256];
    const float ds = (float)dstep[b];
    {
        float t1 = ds * w_emb1[tid] + b_emb1[tid];
        float sg = 1.0f / (1.0f + expf(-t1));
        h[tid] = t1 * sg;               // silu
    }
    __syncthreads();
    {
        float s = b_emb2[tid];
        const float* wrow = w_emb2 + tid * 256;
        for (int c = 0; c < 256; ++c) s += h[c] * wrow[c];
        emb[tid] = s;
    }
    __syncthreads();
    {
        float s = b_proj[tid];
        const float* wrow = w_proj + tid * 256;
        for (int c = 0; c < 256; ++c) s += emb[c] * wrow[c];
        proj[tid] = s;
    }
    __syncthreads();
    for (int i = tid; i < 512 * 3; i += 256) {
        int o = i / 3, k = i - o * 3;
        float s = (k == 1) ? b_conv[o] : 0.0f;
        const float* wrow = w_conv + (size_t)o * 768 + k;
        for (int c = 0; c < 256; ++c) s += proj[c] * wrow[c * 3];
        pk[(size_t)b * 1536 + i] = s;
    }
}

// ---------------- Kernel B: conv (C->2C, 3-tap) + LIF + z ----------------
// Block: 128 conv-out channels (64 gate/filt PAIRS via ob 0..3) x 128 l, loops t=0..3.
// Thread: 8 paired channels (og*8+j) x 8 l (two 4-l groups 64 apart).
// Channel map for oo = og*8+j: ch = g0 + 4*og + (j&3) + ((j&4)?256:0), g0 = ob*64.
// x staged via global_load_lds into linear rows of stride 140 (col 0 <-> l0-8).

#define XS_STRIDE 140

__device__ __forceinline__ void gll16(const float* g, float* l) {
    __builtin_amdgcn_global_load_lds(
        (const __attribute__((address_space(1))) void*)g,
        (__attribute__((address_space(3))) void*)l, 16, 0, 0);
}

__global__ __launch_bounds__(256, 2) void conv_lif_kernel(
    const float* __restrict__ x,
    const float* __restrict__ w_conv,
    const float* __restrict__ pk,
    __hip_bfloat16* __restrict__ zbuf)
{
    const int lb = blockIdx.x;   // 0..15
    const int ob = blockIdx.y;   // 0..3
    const int b  = blockIdx.z;   // 0..15
    const int l0 = lb * 128;
    const int g0 = ob * 64;      // gate channel base (pairs base)
    const int tid = threadIdx.x;
    const int lg4 = (tid & 15) * 4;   // l sub-offset
    const int og8 = (tid >> 4) * 8;   // oo base (8 per thread)

    __shared__ float xs[32 * XS_STRIDE + 128];  // +128 floats pad for tail-wave gll writes
    __shared__ float wsh[96 * 128];             // [ck = c_local*3+k][oo 0..127]
    __shared__ float pksh[128 * 4];             // [oo] {p0+p1+p2, p0, p2, pad}

    // pk staging (once; covered by first barrier in cc loop)
    if (tid < 128) {
        int j = tid & 7, ogg = tid >> 3;
        int ch = g0 + ogg * 4 + (j & 3) + ((j & 4) ? 256 : 0);
        const float* p = pk + (size_t)b * 1536 + ch * 3;
        float p0 = p[0], p1 = p[1], p2 = p[2];
        pksh[tid * 4 + 0] = p0 + p1 + p2;
        pksh[tid * 4 + 1] = p0;
        pksh[tid * 4 + 2] = p2;
    }

    // W stage mapping: w_oo = tid>>1 (bank = w_oo mod 32 -> 2-way, conflict-free)
    const int w_oo = tid >> 1;
    const int w_sub = tid & 1;
    const int w_j = w_oo & 7, w_og = w_oo >> 3;
    const int w_ch = g0 + w_og * 4 + (w_j & 3) + ((w_j & 4) ? 256 : 0);

    const float e0 = (lb == 0  && lg4 == 0)  ? 1.0f : 0.0f;  // l==0 lane flag (g=0,lj=0)
    const float e1 = (lb == 15 && lg4 == 60) ? 1.0f : 0.0f;  // l==2047 lane flag (g=1,lj=3)

    float v[64];
#pragma unroll
    for (int i = 0; i < 64; ++i) v[i] = 0.0f;

    const float Z01 = 0.3807970780f;   // sigmoid(0)*tanh(1)
    const float Z11 = 0.5567699413f;   // sigmoid(1)*tanh(1)

    for (int t = 0; t < T_STEPS; ++t) {
        float acc[64];
#pragma unroll
        for (int i = 0; i < 64; ++i) acc[i] = 0.0f;

        const float* xsl = x + (size_t)(t * BB + b) * C_CH * LL;

        for (int cc = 0; cc < 8; ++cc) {
            __syncthreads();   // previous iteration's readers done
            // ---- x: global -> LDS direct (rows c = cc*32..+31, cols l0-8 .. l0+131) ----
            {
                const float* xc = xsl + (size_t)cc * 32 * LL;
#pragma unroll
                for (int r = 0; r < 4; ++r) {
                    int chunk = r * 256 + tid;          // 16B chunks, 35 per row
                    int row = chunk / 35;
                    int c16 = chunk - row * 35;
                    int off = l0 - 8 + c16 * 4;
                    off = (off < 0) ? 0 : ((off > LL - 4) ? (LL - 4) : off);
                    gll16(xc + (size_t)row * LL + off, &xs[chunk * 4]);
                }
                if (tid < 128) {                        // tail: chunks 1024..1151 (>=1120 -> pad)
                    int chunk = 1024 + tid;
                    int row = chunk / 35;
                    int c16 = chunk - row * 35;
                    if (row > 31) { row = 31; }
                    int off = l0 - 8 + c16 * 4;
                    off = (off < 0) ? 0 : ((off > LL - 4) ? (LL - 4) : off);
                    gll16(xc + (size_t)row * LL + off, &xs[chunk * 4]);
                }
            }
            // ---- W: global (L2-hot) -> regs -> LDS [ck][128], 2-way banks ----
            {
                const float* wsrc = w_conv + (size_t)w_ch * 768 + (cc * 32 + w_sub * 16) * 3;
                const int wb = w_sub * 48;
#pragma unroll
                for (int q = 0; q < 12; ++q) {
                    float4 w4 = *(const float4*)(wsrc + q * 4);
                    wsh[(wb + q * 4 + 0) * 128 + w_oo] = w4.x;
                    wsh[(wb + q * 4 + 1) * 128 + w_oo] = w4.y;
                    wsh[(wb + q * 4 + 2) * 128 + w_oo] = w4.z;
                    wsh[(wb + q * 4 + 3) * 128 + w_oo] = w4.w;
                }
            }
            __syncthreads();   // waits vmcnt(0)+lgkmcnt(0): gll + ds_writes complete
            // ---- halo zeros (edge blocks only; wave-uniform branch) ----
            if (lb == 0) {
                if (tid < 32) xs[tid * XS_STRIDE + 7] = 0.0f;     // l = -1
                __syncthreads();
            } else if (lb == 15) {
                if (tid < 32) xs[tid * XS_STRIDE + 136] = 0.0f;   // l = 2048
                __syncthreads();
            }
            // ---- accumulate ----
            for (int cl = 0; cl < 32; ++cl) {
                const int xb = cl * XS_STRIDE + lg4;
                float xw0[6], xw1[6];
                {
                    float4 xa = *(const float4*)&xs[xb + 8];     // x[L..L+3], g=0
                    xw0[0] = xs[xb + 7];                         // x[L-1]
                    xw0[1] = xa.x; xw0[2] = xa.y; xw0[3] = xa.z; xw0[4] = xa.w;
                    xw0[5] = xs[xb + 12];                        // x[L+4]
                }
                {
                    float4 xa = *(const float4*)&xs[xb + 72];    // g=1 (l +64)
                    xw1[0] = xs[xb + 71];
                    xw1[1] = xa.x; xw1[2] = xa.y; xw1[3] = xa.z; xw1[4] = xa.w;
                    xw1[5] = xs[xb + 76];
                }
#pragma unroll
                for (int k = 0; k < 3; ++k) {
                    float4 wa  = *(const float4*)&wsh[(cl * 3 + k) * 128 + og8];
                    float4 wb4 = *(const float4*)&wsh[(cl * 3 + k) * 128 + og8 + 4];
                    float wv[8] = { wa.x, wa.y, wa.z, wa.w, wb4.x, wb4.y, wb4.z, wb4.w };
#pragma unroll
                    for (int j = 0; j < 8; ++j) {
#pragma unroll
                        for (int lj = 0; lj < 4; ++lj) {
                            acc[j * 4 + lj]      += wv[j] * xw0[lj + k];
                            acc[32 + j * 4 + lj] += wv[j] * xw1[lj + k];
                        }
                    }
                }
            }
        }

        // ---- LIF update + spikes (spikes overwrite acc to cap VGPR pressure) ----
#pragma unroll
        for (int g = 0; g < 2; ++g) {
#pragma unroll
            for (int j = 0; j < 8; ++j) {
                const int oo = og8 + j;
                const float psum = pksh[oo * 4 + 0];
#pragma unroll
                for (int lj = 0; lj < 4; ++lj) {
                    const int idx = g * 32 + j * 4 + lj;
                    float y2 = acc[idx] + psum;
                    if (g == 0 && lj == 0) y2 -= e0 * pksh[oo * 4 + 1];  // drop p0 at l==0
                    if (g == 1 && lj == 3) y2 -= e1 * pksh[oo * 4 + 2];  // drop p2 at l==2047
                    float vv = v[idx];
                    vv = vv + (y2 - vv) / 1.2f;            // exact division like reference
                    float s = (vv >= 0.5f) ? 1.0f : 0.0f;  // heaviside forward value
                    acc[idx] = s;
                    v[idx] = vv * (1.0f - s);
                }
            }
        }

        // ---- z = f(gate spike, filt spike), write bf16 ----
#pragma unroll
        for (int g = 0; g < 2; ++g) {
#pragma unroll
            for (int jp = 0; jp < 4; ++jp) {
                union { __hip_bfloat16 h[4]; uint2 u; } pv;
#pragma unroll
                for (int lj = 0; lj < 4; ++lj) {
                    float gg = acc[g * 32 + jp * 4 + lj];
                    float ff = acc[g * 32 + (jp + 4) * 4 + lj];
                    float z = (ff != 0.0f) ? ((gg != 0.0f) ? Z11 : Z01) : 0.0f;
                    pv.h[lj] = __float2bfloat16(z);
                }
                int ch = g0 + (og8 >> 1) + jp;  // = g0 + og*4 + jp (gate channel / z channel)
                size_t zi = ((size_t)(t * BB + b) * C_CH + ch) * LL + l0 + g * 64 + lg4;
                *(uint2*)((char*)zbuf + zi * 2) = pv.u;
            }
        }
    }
}

// ---------------- Kernel C: res/skip GEMMs + bias + x add ----------------
// Block: 64 o x 128 l for one (t,b). Thread: 4o x 8l (two 4-l groups), dual acc.
__global__ __launch_bounds__(256) void out_gemm_kernel(
    const float* __restrict__ x,
    const __hip_bfloat16* __restrict__ zbuf,
    const float* __restrict__ w_skip, const float* __restrict__ b_skip,
    const float* __restrict__ w_res,  const float* __restrict__ b_res,
    float* __restrict__ out)
{
    const int lb  = blockIdx.x;  // 0..15
    const int obk = blockIdx.y;  // 0..3
    const int tb  = blockIdx.z;  // 0..63 = t*16+b
    const int l0 = lb * 128, o0 = obk * 64;
    const int tid = threadIdx.x;
    const int lg = tid & 15, og = tid >> 4;

    __shared__ float zsh[32 * 132];
    __shared__ float wrh[32 * 68];
    __shared__ float wkh[32 * 68];

    float accR[32], accS[32];
#pragma unroll
    for (int i = 0; i < 32; ++i) { accR[i] = 0.0f; accS[i] = 0.0f; }

    // z staging map: row = tid>>3 (0..31), colg = tid&7 -> 16 contiguous bf16
    const int z_row = tid >> 3;
    const int z_colg = tid & 7;

    for (int cc = 0; cc < 8; ++cc) {
        __syncthreads();
        {
            const __hip_bfloat16* zb = zbuf + ((size_t)tb * C_CH + cc * 32 + z_row) * LL
                                     + l0 + z_colg * 16;
#pragma unroll
            for (int half = 0; half < 2; ++half) {
                uint4 raw = *(const uint4*)((const char*)zb + half * 16);
                const unsigned int w[4] = { raw.x, raw.y, raw.z, raw.w };
                float f[8];
#pragma unroll
                for (int q = 0; q < 4; ++q) {
                    union { float fv; unsigned int uv; } lo, hi;
                    lo.uv = (w[q] & 0xFFFFu) << 16;
                    hi.uv = (w[q] & 0xFFFF0000u);
                    f[q * 2 + 0] = lo.fv;
                    f[q * 2 + 1] = hi.fv;
                }
                float4* dst = (float4*)&zsh[z_row * 132 + z_colg * 16 + half * 8];
                dst[0] = make_float4(f[0], f[1], f[2], f[3]);
                dst[1] = make_float4(f[4], f[5], f[6], f[7]);
            }
            for (int i = tid; i < 2048; i += 256) {
                int oo = i >> 5, cl = i & 31;
                int c = cc * 32 + cl;
                wrh[cl * 68 + oo] = w_res[(size_t)(o0 + oo) * 256 + c];
                wkh[cl * 68 + oo] = w_skip[(size_t)(o0 + oo) * 256 + c];
            }
        }
        __syncthreads();
        for (int cl = 0; cl < 32; ++cl) {
            float4 z0 = *(const float4*)&zsh[cl * 132 + lg * 4];
            float4 z1 = *(const float4*)&zsh[cl * 132 + 64 + lg * 4];
            float4 r4 = *(const float4*)&wrh[cl * 68 + og * 4];
            float4 k4 = *(const float4*)&wkh[cl * 68 + og * 4];
            float zz0[4] = { z0.x, z0.y, z0.z, z0.w };
            float zz1[4] = { z1.x, z1.y, z1.z, z1.w };
            float rr[4] = { r4.x, r4.y, r4.z, r4.w };
            float kk[4] = { k4.x, k4.y, k4.z, k4.w };
#pragma unroll
            for (int j = 0; j < 4; ++j) {
#pragma unroll
                for (int lj = 0; lj < 4; ++lj) {
                    accR[j * 4 + lj]      += rr[j] * zz0[lj];
                    accS[j * 4 + lj]      += kk[j] * zz0[lj];
                    accR[16 + j * 4 + lj] += rr[j] * zz1[lj];
                    accS[16 + j * 4 + lj] += kk[j] * zz1[lj];
                }
            }
        }
    }

    const size_t base = (size_t)tb * C_CH * LL;
#pragma unroll
    for (int g = 0; g < 2; ++g) {
#pragma unroll
        for (int j = 0; j < 4; ++j) {
            int o = o0 + og * 4 + j;
            float br = b_res[o], bs = b_skip[o];
            size_t idx = base + (size_t)o * LL + l0 + g * 64 + lg * 4;
            float4 x4 = *(const float4*)&x[idx];
            float4 ro, so;
            ro.x = x4.x + accR[g * 16 + j * 4 + 0] + br;
            ro.y = x4.y + accR[g * 16 + j * 4 + 1] + br;
            ro.z = x4.z + accR[g * 16 + j * 4 + 2] + br;
            ro.w = x4.w + accR[g * 16 + j * 4 + 3] + br;
            so.x = accS[g * 16 + j * 4 + 0] + bs;
            so.y = accS[g * 16 + j * 4 + 1] + bs;
            so.z = accS[g * 16 + j * 4 + 2] + bs;
            so.w = accS[g * 16 + j * 4 + 3] + bs;
            *(float4*)&out[idx] = ro;
            *(float4*)&out[OUT_HALF + idx] = so;
        }
    }
}

extern "C" void kernel_launch(void* const* d_in, const int* in_sizes, int n_in,
                              void* d_out, int out_size, void* d_ws, size_t ws_size,
                              hipStream_t stream) {
    const float* x       = (const float*)d_in[0];
    const int*   dstep   = (const int*)d_in[1];
    const float* w_emb1  = (const float*)d_in[2];
    const float* b_emb1  = (const float*)d_in[3];
    const float* w_emb2  = (const float*)d_in[4];
    const float* b_emb2  = (const float*)d_in[5];
    const float* w_proj  = (const float*)d_in[6];
    const float* b_proj  = (const float*)d_in[7];
    const float* w_conv  = (const float*)d_in[8];
    const float* b_conv  = (const float*)d_in[9];
    const float* w_skip  = (const float*)d_in[10];
    const float* b_skip  = (const float*)d_in[11];
    const float* w_res   = (const float*)d_in[12];
    const float* b_res   = (const float*)d_in[13];
    float* out = (float*)d_out;

    // ws layout: pk floats [16][512][3] at 0 (96 KiB), zbuf bf16 [4][16][256][2048] at 128 KiB
    float* pk = (float*)d_ws;
    __hip_bfloat16* zbuf = (__hip_bfloat16*)((char*)d_ws + 131072);

    embed_proj_kernel<<<BB, 256, 0, stream>>>(dstep, w_emb1, b_emb1, w_emb2, b_emb2,
                                              w_proj, b_proj, w_conv, b_conv, pk);
    conv_lif_kernel<<<dim3(LL / 128, 4, BB), 256, 0, stream>>>(x, w_conv, pk, zbuf);
    out_gemm_kernel<<<dim3(LL / 128, C_CH / 64, T_STEPS * BB), 256, 0, stream>>>(
        x, zbuf, w_skip, b_skip, w_res, b_res, out);
}

// Round 2
// 1830.301 us; speedup vs baseline: 1.3006x; 1.0844x over previous
//
#include <hip/hip_runtime.h>
#include <hip/hip_bf16.h>

// Shapes (fixed): T=4, B=16, C=256 (gate/filt each), O=2C=512 conv-out, L=2048.
// TAU=1.2, VTH=0.5. Spikes are exactly (v >= 0.5) in forward.
// z = sigmoid(gate)*tanh(filt) with gate,filt in {0,1} -> z in {0, Z01, Z11}.

#define T_STEPS 4
#define BB 16
#define C_CH 256
#define O_CH 512
#define LL 2048
#define OUT_HALF 33554432  // T*B*C*L

typedef __bf16 bf16x8 __attribute__((ext_vector_type(8)));
typedef float f32x4 __attribute__((ext_vector_type(4)));

// ---------------- Kernel A: embedding MLP -> proj -> pk[b][o][k] ----------------
__global__ __launch_bounds__(256) void embed_proj_kernel(
    const int* __restrict__ dstep,
    const float* __restrict__ w_emb1, const float* __restrict__ b_emb1,
    const float* __restrict__ w_emb2, const float* __restrict__ b_emb2,
    const float* __restrict__ w_proj, const float* __restrict__ b_proj,
    const float* __restrict__ w_conv, const float* __restrict__ b_conv,
    float* __restrict__ pk)
{
    const int b = blockIdx.x;
    const int tid = threadIdx.x;
    __shared__ float h[256], emb[256], proj[256];
    const float ds = (float)dstep[b];
    {
        float t1 = ds * w_emb1[tid] + b_emb1[tid];
        float sg = 1.0f / (1.0f + expf(-t1));
        h[tid] = t1 * sg;               // silu
    }
    __syncthreads();
    {
        float s = b_emb2[tid];
        const float* wrow = w_emb2 + tid * 256;
        for (int c = 0; c < 256; ++c) s += h[c] * wrow[c];
        emb[tid] = s;
    }
    __syncthreads();
    {
        float s = b_proj[tid];
        const float* wrow = w_proj + tid * 256;
        for (int c = 0; c < 256; ++c) s += emb[c] * wrow[c];
        proj[tid] = s;
    }
    __syncthreads();
    for (int i = tid; i < 512 * 3; i += 256) {
        int o = i / 3, k = i - o * 3;
        float s = (k == 1) ? b_conv[o] : 0.0f;
        const float* wrow = w_conv + (size_t)o * 768 + k;
        for (int c = 0; c < 256; ++c) s += proj[c] * wrow[c * 3];
        pk[(size_t)b * 1536 + i] = s;
    }
}

// ---------------- Kernel B: conv (C->2C, 3-tap) + LIF + z ----------------
// Block: 128 conv-out channels (64 gate/filt PAIRS via ob 0..3) x 128 l, loops t=0..3.
// Thread: 8 paired channels (og*8+j) x 8 l (two 4-l groups 64 apart).
// Channel map for oo = og*8+j: ch = g0 + 4*og + (j&3) + ((j&4)?256:0), g0 = ob*64.
// c-chunks of 16 rows -> LDS 35.1 KB -> 4 blocks/CU.
// z written in fragment-major layout z'[tb][c>>5][l][c&31] bf16 for MFMA kernel C.

#define XS_STRIDE 140

__device__ __forceinline__ void gll16(const float* g, float* l) {
    __builtin_amdgcn_global_load_lds(
        (const __attribute__((address_space(1))) void*)g,
        (__attribute__((address_space(3))) void*)l, 16, 0, 0);
}

__global__ __launch_bounds__(256, 4) void conv_lif_kernel(
    const float* __restrict__ x,
    const float* __restrict__ w_conv,
    const float* __restrict__ pk,
    __hip_bfloat16* __restrict__ zbuf)
{
    const int lb = blockIdx.x;   // 0..15
    const int ob = blockIdx.y;   // 0..3
    const int b  = blockIdx.z;   // 0..15
    const int l0 = lb * 128;
    const int g0 = ob * 64;      // gate channel base (pairs base)
    const int tid = threadIdx.x;
    const int lg4 = (tid & 15) * 4;   // l sub-offset
    const int og  = tid >> 4;         // 0..15
    const int og8 = og * 8;           // oo base (8 per thread)

    __shared__ float xs[16 * XS_STRIDE];   // 2240 floats: 16 c-rows x 140 (col0 = l0-8)
    __shared__ float wsh[48 * 128];        // [ck = c_local*3+k][oo 0..127]
    __shared__ float pksh[128 * 3];        // [oo] {p0+p1+p2, p0, p2} stride 3 (bank-safe)

    // pk staging (once; covered by first barrier in cc loop)
    if (tid < 128) {
        int j = tid & 7, ogg = tid >> 3;
        int ch = g0 + ogg * 4 + (j & 3) + ((j & 4) ? 256 : 0);
        const float* p = pk + (size_t)b * 1536 + ch * 3;
        float p0 = p[0], p1 = p[1], p2 = p[2];
        pksh[tid * 3 + 0] = p0 + p1 + p2;
        pksh[tid * 3 + 1] = p0;
        pksh[tid * 3 + 2] = p2;
    }

    // W stage mapping: w_oo = tid>>1 (bank = w_oo mod 32 -> 2-way, conflict-free)
    const int w_oo = tid >> 1;
    const int w_sub = tid & 1;
    const int w_j = w_oo & 7, w_og = w_oo >> 3;
    const int w_ch = g0 + w_og * 4 + (w_j & 3) + ((w_j & 4) ? 256 : 0);

    const float e0 = (lb == 0  && lg4 == 0)  ? 1.0f : 0.0f;  // l==0 lane flag (g=0,lj=0)
    const float e1 = (lb == 15 && lg4 == 60) ? 1.0f : 0.0f;  // l==2047 lane flag (g=1,lj=3)

    float v[64];
#pragma unroll
    for (int i = 0; i < 64; ++i) v[i] = 0.0f;

    const float Z01 = 0.3807970780f;   // sigmoid(0)*tanh(1)
    const float Z11 = 0.5567699413f;   // sigmoid(1)*tanh(1)

    for (int t = 0; t < T_STEPS; ++t) {
        float acc[64];
#pragma unroll
        for (int i = 0; i < 64; ++i) acc[i] = 0.0f;

        const float* xsl = x + (size_t)(t * BB + b) * C_CH * LL;

        for (int cc = 0; cc < 16; ++cc) {
            __syncthreads();   // previous iteration's readers done
            // ---- x: global -> LDS direct (rows c = cc*16..+15, cols l0-8 .. l0+131) ----
            {
                const float* xc = xsl + (size_t)cc * 16 * LL;
#pragma unroll
                for (int r = 0; r < 2; ++r) {
                    int chunk = r * 256 + tid;          // 16B chunks, 35 per row, 560 total
                    int row = chunk / 35;
                    int c16 = chunk - row * 35;
                    int off = l0 - 8 + c16 * 4;
                    off = (off < 0) ? 0 : ((off > LL - 4) ? (LL - 4) : off);
                    gll16(xc + (size_t)row * LL + off, &xs[chunk * 4]);
                }
                if (tid < 48) {
                    int chunk = 512 + tid;
                    int row = chunk / 35;
                    int c16 = chunk - row * 35;
                    int off = l0 - 8 + c16 * 4;
                    off = (off < 0) ? 0 : ((off > LL - 4) ? (LL - 4) : off);
                    gll16(xc + (size_t)row * LL + off, &xs[chunk * 4]);
                }
            }
            // ---- W: global (L2-hot) -> regs -> LDS [ck][128], 2-way banks ----
            {
                const float* wsrc = w_conv + (size_t)w_ch * 768 + (cc * 16 + w_sub * 8) * 3;
                const int wb = w_sub * 24;
#pragma unroll
                for (int q = 0; q < 6; ++q) {
                    float4 w4 = *(const float4*)(wsrc + q * 4);
                    wsh[(wb + q * 4 + 0) * 128 + w_oo] = w4.x;
                    wsh[(wb + q * 4 + 1) * 128 + w_oo] = w4.y;
                    wsh[(wb + q * 4 + 2) * 128 + w_oo] = w4.z;
                    wsh[(wb + q * 4 + 3) * 128 + w_oo] = w4.w;
                }
            }
            __syncthreads();   // waits vmcnt(0)+lgkmcnt(0): gll + ds_writes complete
            // ---- halo zeros (edge blocks only; wave-uniform branch) ----
            if (lb == 0) {
                if (tid < 16) xs[tid * XS_STRIDE + 7] = 0.0f;     // l = -1
                __syncthreads();
            } else if (lb == 15) {
                if (tid < 16) xs[tid * XS_STRIDE + 136] = 0.0f;   // l = 2048
                __syncthreads();
            }
            // ---- accumulate ----
            for (int cl = 0; cl < 16; ++cl) {
                const int xb = cl * XS_STRIDE + lg4;
                float xw0[6], xw1[6];
                {
                    float4 xa = *(const float4*)&xs[xb + 8];     // x[L..L+3], g=0
                    xw0[0] = xs[xb + 7];                         // x[L-1]
                    xw0[1] = xa.x; xw0[2] = xa.y; xw0[3] = xa.z; xw0[4] = xa.w;
                    xw0[5] = xs[xb + 12];                        // x[L+4]
                }
                {
                    float4 xa = *(const float4*)&xs[xb + 72];    // g=1 (l +64)
                    xw1[0] = xs[xb + 71];
                    xw1[1] = xa.x; xw1[2] = xa.y; xw1[3] = xa.z; xw1[4] = xa.w;
                    xw1[5] = xs[xb + 76];
                }
#pragma unroll
                for (int k = 0; k < 3; ++k) {
                    float4 wa  = *(const float4*)&wsh[(cl * 3 + k) * 128 + og8];
                    float4 wb4 = *(const float4*)&wsh[(cl * 3 + k) * 128 + og8 + 4];
                    float wv[8] = { wa.x, wa.y, wa.z, wa.w, wb4.x, wb4.y, wb4.z, wb4.w };
#pragma unroll
                    for (int j = 0; j < 8; ++j) {
#pragma unroll
                        for (int lj = 0; lj < 4; ++lj) {
                            acc[j * 4 + lj]      += wv[j] * xw0[lj + k];
                            acc[32 + j * 4 + lj] += wv[j] * xw1[lj + k];
                        }
                    }
                }
            }
        }

        // ---- LIF update + spikes (spikes overwrite acc to cap VGPR pressure) ----
#pragma unroll
        for (int g = 0; g < 2; ++g) {
#pragma unroll
            for (int j = 0; j < 8; ++j) {
                const int oo = og8 + j;
                const float psum = pksh[oo * 3 + 0];
#pragma unroll
                for (int lj = 0; lj < 4; ++lj) {
                    const int idx = g * 32 + j * 4 + lj;
                    float y2 = acc[idx] + psum;
                    if (g == 0 && lj == 0) y2 -= e0 * pksh[oo * 3 + 1];  // drop p0 at l==0
                    if (g == 1 && lj == 3) y2 -= e1 * pksh[oo * 3 + 2];  // drop p2 at l==2047
                    float vv = v[idx];
                    vv = vv + (y2 - vv) / 1.2f;            // exact division like reference
                    float s = (vv >= 0.5f) ? 1.0f : 0.0f;  // heaviside forward value
                    acc[idx] = s;
                    v[idx] = vv * (1.0f - s);
                }
            }
        }

        // ---- z = f(gate spike, filt spike), write bf16 in fragment-major layout ----
        // z'[(t*16+b)][c>>5][l][c&31]; this thread's channels c = g0+og*4+jp, jp=0..3
        {
            const int kkw = ob * 2 + (og >> 3);
            const int ci0 = (og & 7) * 4;
#pragma unroll
            for (int g = 0; g < 2; ++g) {
#pragma unroll
                for (int lj = 0; lj < 4; ++lj) {
                    union { __hip_bfloat16 h[4]; uint2 u; } pv;
#pragma unroll
                    for (int jp = 0; jp < 4; ++jp) {
                        float gg = acc[g * 32 + jp * 4 + lj];
                        float ff = acc[g * 32 + (jp + 4) * 4 + lj];
                        float z = (ff != 0.0f) ? ((gg != 0.0f) ? Z11 : Z01) : 0.0f;
                        pv.h[jp] = __float2bfloat16(z);
                    }
                    int l = l0 + g * 64 + lg4 + lj;
                    size_t zi = (((size_t)(t * BB + b) * 8 + kkw) * 2048 + l) * 32 + ci0;
                    *(uint2*)((char*)zbuf + zi * 2) = pv.u;
                }
            }
        }
    }
}

// ---------------- Kernel C: res/skip GEMMs via MFMA + bias + x add ----------------
// Block: 64 o x 128 l for one (t,b); 4 waves, each 32 o x 64 l.
// A = W[o][c] fp32 -> bf16 hi+lo split (2-pass MFMA, ~2^-17 relative error).
// B = z' fragment-major bf16 (coalesced uint4 loads). D layout: row=(lane>>4)*4+r, col=lane&15.
__device__ __forceinline__ void make_afrag(const float* wp, bf16x8& hi, bf16x8& lo) {
    float4 f0 = *(const float4*)wp;
    float4 f1 = *(const float4*)(wp + 4);
    float f[8] = { f0.x, f0.y, f0.z, f0.w, f1.x, f1.y, f1.z, f1.w };
    union { __bf16 h[8]; bf16x8 v; } H, L;
#pragma unroll
    for (int i = 0; i < 8; ++i) {
        __bf16 hv = (__bf16)f[i];
        H.h[i] = hv;
        L.h[i] = (__bf16)(f[i] - (float)hv);
    }
    hi = H.v; lo = L.v;
}

__global__ __launch_bounds__(256, 2) void out_gemm_kernel(
    const float* __restrict__ x,
    const __hip_bfloat16* __restrict__ zbuf,
    const float* __restrict__ w_skip, const float* __restrict__ b_skip,
    const float* __restrict__ w_res,  const float* __restrict__ b_res,
    float* __restrict__ out)
{
    const int lb  = blockIdx.x;  // 0..15
    const int obk = blockIdx.y;  // 0..3
    const int tb  = blockIdx.z;  // 0..63 = t*16+b
    const int l0 = lb * 128, o0 = obk * 64;
    const int tid = threadIdx.x;
    const int lane = tid & 63;
    const int wave = tid >> 6;
    const int wo = wave & 1, wl = wave >> 1;
    const int r16 = lane & 15;   // fragment row/col index
    const int kq  = lane >> 4;   // 0..3 k-quarter

    const int obase = o0 + wo * 32;
    const int lbase = l0 + wl * 64;

    const f32x4 vzero = { 0.0f, 0.0f, 0.0f, 0.0f };
    f32x4 accR[2][4], accS[2][4];
#pragma unroll
    for (int a = 0; a < 2; ++a)
#pragma unroll
        for (int c = 0; c < 4; ++c) { accR[a][c] = vzero; accS[a][c] = vzero; }

    // B: lane reads z[c = kk*32 + kq*8 + i][l = lbase + ls*16 + r16]
    const char* zb = (const char*)zbuf
        + (((size_t)tb * 8) * 2048 + (size_t)lbase + r16) * 64
        + (size_t)kq * 16;
    // A: lane reads W[obase + osub*16 + r16][kk*32 + kq*8 + i]
    const float* wrp = w_res  + (size_t)(obase + r16) * 256 + kq * 8;
    const float* wkp = w_skip + (size_t)(obase + r16) * 256 + kq * 8;

#pragma unroll
    for (int kk = 0; kk < 8; ++kk) {
        bf16x8 Bv[4];
#pragma unroll
        for (int ls = 0; ls < 4; ++ls) {
            union { uint4 u; bf16x8 v; } t2;
            t2.u = *(const uint4*)(zb + (size_t)kk * (2048 * 64) + ls * (16 * 64));
            Bv[ls] = t2.v;
        }
        bf16x8 AhR[2], AlR[2], AhS[2], AlS[2];
#pragma unroll
        for (int osub = 0; osub < 2; ++osub) {
            make_afrag(wrp + osub * (16 * 256) + kk * 32, AhR[osub], AlR[osub]);
            make_afrag(wkp + osub * (16 * 256) + kk * 32, AhS[osub], AlS[osub]);
        }
#pragma unroll
        for (int osub = 0; osub < 2; ++osub) {
#pragma unroll
            for (int ls = 0; ls < 4; ++ls) {
                accR[osub][ls] = __builtin_amdgcn_mfma_f32_16x16x32_bf16(
                    AhR[osub], Bv[ls], accR[osub][ls], 0, 0, 0);
                accR[osub][ls] = __builtin_amdgcn_mfma_f32_16x16x32_bf16(
                    AlR[osub], Bv[ls], accR[osub][ls], 0, 0, 0);
                accS[osub][ls] = __builtin_amdgcn_mfma_f32_16x16x32_bf16(
                    AhS[osub], Bv[ls], accS[osub][ls], 0, 0, 0);
                accS[osub][ls] = __builtin_amdgcn_mfma_f32_16x16x32_bf16(
                    AlS[osub], Bv[ls], accS[osub][ls], 0, 0, 0);
            }
        }
    }

    const size_t base = (size_t)tb * C_CH * LL;
#pragma unroll
    for (int osub = 0; osub < 2; ++osub) {
#pragma unroll
        for (int r = 0; r < 4; ++r) {
            const int o = obase + osub * 16 + kq * 4 + r;
            const float br = b_res[o], bs = b_skip[o];
#pragma unroll
            for (int ls = 0; ls < 4; ++ls) {
                const int l = lbase + ls * 16 + r16;
                const size_t idx = base + (size_t)o * LL + l;
                out[idx] = x[idx] + accR[osub][ls][r] + br;
                out[OUT_HALF + idx] = accS[osub][ls][r] + bs;
            }
        }
    }
}

extern "C" void kernel_launch(void* const* d_in, const int* in_sizes, int n_in,
                              void* d_out, int out_size, void* d_ws, size_t ws_size,
                              hipStream_t stream) {
    const float* x       = (const float*)d_in[0];
    const int*   dstep   = (const int*)d_in[1];
    const float* w_emb1  = (const float*)d_in[2];
    const float* b_emb1  = (const float*)d_in[3];
    const float* w_emb2  = (const float*)d_in[4];
    const float* b_emb2  = (const float*)d_in[5];
    const float* w_proj  = (const float*)d_in[6];
    const float* b_proj  = (const float*)d_in[7];
    const float* w_conv  = (const float*)d_in[8];
    const float* b_conv  = (const float*)d_in[9];
    const float* w_skip  = (const float*)d_in[10];
    const float* b_skip  = (const float*)d_in[11];
    const float* w_res   = (const float*)d_in[12];
    const float* b_res   = (const float*)d_in[13];
    float* out = (float*)d_out;

    // ws layout: pk floats [16][512][3] at 0 (96 KiB), z' bf16 [64][8][2048][32] at 128 KiB
    float* pk = (float*)d_ws;
    __hip_bfloat16* zbuf = (__hip_bfloat16*)((char*)d_ws + 131072);

    embed_proj_kernel<<<BB, 256, 0, stream>>>(dstep, w_emb1, b_emb1, w_emb2, b_emb2,
                                              w_proj, b_proj, w_conv, b_conv, pk);
    conv_lif_kernel<<<dim3(LL / 128, 4, BB), 256, 0, stream>>>(x, w_conv, pk, zbuf);
    out_gemm_kernel<<<dim3(LL / 128, C_CH / 64, T_STEPS * BB), 256, 0, stream>>>(
        x, zbuf, w_skip, b_skip, w_res, b_res, out);
}